// Round 20
// baseline (26.228 us; speedup 1.0000x reference)
//
#include <hip/hip_runtime.h>
#include <hip/hip_fp16.h>

// Problem constants (match reference)
constexpr int B  = 4;
constexpr int C  = 3;
constexpr int F  = 5;
constexpr int HO = 256;
constexpr int WO = 256;
constexpr int HI = HO + F - 1; // 260
constexpr int WI = WO + F - 1; // 260
constexpr int P  = HO * WO;    // 65536 pixels per (b, map)
constexpr int FF = F * F;      // 25
constexpr int PI = HI * WI;    // 67600 input pixels per (b, c)

// R20: TLP x1.5 on top of R18's ILP. Patch 64x2 (128 px), block = 256 thr =
// 4 waves; each wave covers the WHOLE patch (row = lane>>5, x = x0+2*(lane&31),
// 2 px/thread) and owns a tap QUARTER (6/6/6/7). Grid 2048 blocks; LDS 16.1KB
// and __launch_bounds__(256,6) -> 6 blocks/CU = 24 waves/CU resident (vs 16).
// Staging/px only +10% (margin amortizes fine at 64 wide). Tap body = R16/R18
// verbatim (1-deep stream prefetch; 2-deep regressed R17). Staging unroll 4
// (R18 win). TSTRIDE mod 16 = 5 (R15 bank-decollision). Margin 5 (R17-valid).
constexpr int TROWS = 17;
constexpr int TCOLS = 79;
constexpr int TSTRIDE = 85;            // 8B units; 85 mod 16 = 5
constexpr int TN = TROWS * TCOLS;      // 1343 entries to stage
constexpr int AMAX = (TROWS - 2) * TSTRIDE + (TCOLS - 2); // 1352

__device__ __forceinline__ float2 ld2(const float* p) {
    return *reinterpret_cast<const float2*>(p);
}

__device__ __forceinline__ uint2 pack3(float a, float b, float c) {
    __half2 ab = __floats2half2_rn(a, b);
    __half2 cz = __floats2half2_rn(c, 0.0f);
    uint2 r;
    r.x = *reinterpret_cast<const unsigned int*>(&ab);
    r.y = *reinterpret_cast<const unsigned int*>(&cz);
    return r;
}

__device__ __forceinline__ void fmacc(uint2 v, float w,
                                      float& a0, float& a1, float& a2) {
    __half2 ab = *reinterpret_cast<const __half2*>(&v.x);
    __half2 cz = *reinterpret_cast<const __half2*>(&v.y);
    // (float)half * f32 + f32 acc -> v_fma_mix_f32
    a0 += __half2float(__low2half(ab))  * w;
    a1 += __half2float(__high2half(ab)) * w;
    a2 += __half2float(__low2half(cz))  * w;
}

__global__ __launch_bounds__(256, 6) void dsepconv_kernel(
    const float* __restrict__ inp,   // (B, C, HI, WI)
    const float* __restrict__ vert,  // (B, F, HO, WO)
    const float* __restrict__ horz,  // (B, F, HO, WO)
    const float* __restrict__ offX,  // -> py (vertical), per reference
    const float* __restrict__ offY,  // -> px (horizontal), per reference
    const float* __restrict__ mask,  // (B, F*F, HO, WO)
    float* __restrict__ out)         // (B, C, HO, WO)
{
    __shared__ uint2 tileq[(TROWS - 1) * TSTRIDE + TCOLS]; // 1439 ent, 11,512 B
    __shared__ float red[3][3][128];                       // 4,608 B

    const int tid  = threadIdx.x;
    const int lane = tid & 63;
    const int wave = tid >> 6;                 // 0..3 == tap quarter
    const int row  = lane >> 5;                // 0..1: y-row in patch
    const int xl   = lane & 31;

    // Grid: bx = b*512 + yblk*4 + xblk ; patch origin (y0, x0)
    const int bx   = blockIdx.x;
    const int x0   = (bx & 3) * 64;
    const int y0   = ((bx >> 2) & 127) * 2;
    const int b    = bx >> 9;

    const float* in0 = inp + (size_t)b * C * PI;
    const float* in1 = in0 + PI;
    const float* in2 = in1 + PI;

    const int x   = x0 + 2 * xl;               // even; this thread: x, x+1
    const int y   = y0 + row;
    const int pix = y * WO + x;

    const float* offXb = offX + (size_t)b * FF * P + pix;
    const float* offYb = offY + (size_t)b * FF * P + pix;
    const float* maskb = mask + (size_t)b * FF * P + pix;
    const float* vb    = vert + (size_t)b * F * P + pix;
    const float* hb    = horz + (size_t)b * F * P + pix;

    const int k0 = wave * 6;
    const int k1 = (wave == 3) ? FF : k0 + 6;

    // ---- Prefetch first tap's streams (drained by the staging barrier) ----
    float2 oy, ox, m, h, v;
    {
        const int i = k0 / F, j = k0 - (k0 / F) * F;
        oy = ld2(offYb + (size_t)k0 * P);
        ox = ld2(offXb + (size_t)k0 * P);
        m  = ld2(maskb + (size_t)k0 * P);
        h  = ld2(hb + (size_t)j * P);
        v  = ld2(vb + (size_t)i * P);
    }

    // ---- Stage tile: rows [y0-6, y0+10], cols [x0-6, x0+72] ----
    // Unroll 4: independent + transient -> loads pipeline, no VGPR growth.
    const int ry0 = y0 - 6;
    const int cx0 = x0 - 6;
#pragma unroll 4
    for (int e = tid; e < TN; e += 256) {
        int trow = e / TCOLS;
        int tcol = e - trow * TCOLS;
        int gy = min(max(ry0 + trow, 0), HI - 1);
        int gx = min(max(cx0 + tcol, 0), WI - 1);
        int g = gy * WI + gx;
        tileq[trow * TSTRIDE + tcol] = pack3(in0[g], in1[g], in2[g]);
    }
    __syncthreads();   // vmcnt(0) drain also completes the stream prefetch

    float acc0a = 0.f, acc1a = 0.f, acc2a = 0.f;
    float acc0b = 0.f, acc1b = 0.f, acc2b = 0.f;

#pragma unroll 1
    for (int k = k0; k < k1; ++k) {
        const int i = k / F;
        const int j = k - i * F;

        // ---- issue NEXT tap's streams (float2, overlap with compute) ----
        const int kn  = (k + 1 < k1) ? k + 1 : k;
        const int in_ = kn / F;
        const int jn  = kn - in_ * F;
        float2 oy_n = ld2(offYb + (size_t)kn * P);
        float2 ox_n = ld2(offXb + (size_t)kn * P);
        float2 m_n  = ld2(maskb + (size_t)kn * P);
        float2 h_n  = ld2(hb + (size_t)jn * P);
        float2 v_n  = ld2(vb + (size_t)in_ * P);

        // ---- coords, pixel A (x) and B (x+1) ----
        // px = clip(offY + x + j - half + 1, 0, WI-1); half = 2
        float pya = fminf(fmaxf(ox.x + (float)(y + i - 1), 0.0f), (float)(HI - 1));
        float pyb = fminf(fmaxf(ox.y + (float)(y + i - 1), 0.0f), (float)(HI - 1));
        float pxa = fminf(fmaxf(oy.x + (float)(x + j - 1), 0.0f), (float)(WI - 1));
        float pxb = fminf(fmaxf(oy.y + (float)(x + j), 0.0f), (float)(WI - 1));

        float lfa = floorf(pxa), tfa = floorf(pya);
        float lfb = floorf(pxb), tfb = floorf(pyb);
        int la = (int)lfa, ta = (int)tfa;
        int lb = (int)lfb, tb = (int)tfb;
        float wxa = 1.0f - (pxa - lfa), wya = 1.0f - (pya - tfa);
        float wxb = 1.0f - (pxb - lfb), wyb = 1.0f - (pyb - tfb);

        int lta = ta - ry0, lla = la - cx0;
        int ltb = tb - ry0, llb = lb - cx0;
        bool oka = ((unsigned)lta <= TROWS - 2) & ((unsigned)lla <= TCOLS - 2);
        bool okb = ((unsigned)ltb <= TROWS - 2) & ((unsigned)llb <= TCOLS - 2);

        int aa = min(max(lta * TSTRIDE + lla, 0), AMAX);
        int ab = min(max(ltb * TSTRIDE + llb, 0), AMAX);

        // ---- 8 gathers issue together; FMAs follow ----
        uint2 ga0 = tileq[aa];
        uint2 ga1 = tileq[aa + 1];
        uint2 ga2 = tileq[aa + TSTRIDE];
        uint2 ga3 = tileq[aa + TSTRIDE + 1];
        uint2 gb0 = tileq[ab];
        uint2 gb1 = tileq[ab + 1];
        uint2 gb2 = tileq[ab + TSTRIDE];
        uint2 gb3 = tileq[ab + TSTRIDE + 1];

        // rare fallback: offset beyond tile margin (~1e-6/sample)
        if (__any(!(oka & okb))) {
            if (!oka) {
                int r  = min(la + 1, WI - 1);
                int bt = min(ta + 1, HI - 1);
                int o0 = ta * WI + la, o1 = ta * WI + r;
                int o2 = bt * WI + la, o3 = bt * WI + r;
                ga0 = pack3(in0[o0], in1[o0], in2[o0]);
                ga1 = pack3(in0[o1], in1[o1], in2[o1]);
                ga2 = pack3(in0[o2], in1[o2], in2[o2]);
                ga3 = pack3(in0[o3], in1[o3], in2[o3]);
            }
            if (!okb) {
                int r  = min(lb + 1, WI - 1);
                int bt = min(tb + 1, HI - 1);
                int o0 = tb * WI + lb, o1 = tb * WI + r;
                int o2 = bt * WI + lb, o3 = bt * WI + r;
                gb0 = pack3(in0[o0], in1[o0], in2[o0]);
                gb1 = pack3(in0[o1], in1[o1], in2[o1]);
                gb2 = pack3(in0[o2], in1[o2], in2[o2]);
                gb3 = pack3(in0[o3], in1[o3], in2[o3]);
            }
        }

        // Bilinear identity: clamped edge => r/bottom weights exactly 0.
        float wA   = v.x * h.x * m.x;
        float wywA = wya * wA;
        float wbwA = wA - wywA;
        float wtlA = wxa * wywA;
        float wtrA = wywA - wtlA;
        float wblA = wxa * wbwA;
        float wbrA = wbwA - wblA;

        float wB   = v.y * h.y * m.y;
        float wywB = wyb * wB;
        float wbwB = wB - wywB;
        float wtlB = wxb * wywB;
        float wtrB = wywB - wtlB;
        float wblB = wxb * wbwB;
        float wbrB = wbwB - wblB;

        fmacc(ga0, wtlA, acc0a, acc1a, acc2a);
        fmacc(ga1, wtrA, acc0a, acc1a, acc2a);
        fmacc(ga2, wblA, acc0a, acc1a, acc2a);
        fmacc(ga3, wbrA, acc0a, acc1a, acc2a);
        fmacc(gb0, wtlB, acc0b, acc1b, acc2b);
        fmacc(gb1, wtrB, acc0b, acc1b, acc2b);
        fmacc(gb2, wblB, acc0b, acc1b, acc2b);
        fmacc(gb3, wbrB, acc0b, acc1b, acc2b);

        // ---- rotate stream pipeline ----
        oy = oy_n; ox = ox_n; m = m_n; h = h_n; v = v_n;
    }

    // ---- Combine 4 tap-quarters: waves 1-3 write partials, wave 0 stores ----
    const int p = row * 64 + 2 * xl;           // pixel index within patch
    if (wave != 0) {
        *reinterpret_cast<float2*>(&red[wave - 1][0][p]) = make_float2(acc0a, acc0b);
        *reinterpret_cast<float2*>(&red[wave - 1][1][p]) = make_float2(acc1a, acc1b);
        *reinterpret_cast<float2*>(&red[wave - 1][2][p]) = make_float2(acc2a, acc2b);
    }
    __syncthreads();

    if (wave == 0) {
        float* ob = out + (size_t)b * C * P + pix;
        float2 r00 = *reinterpret_cast<const float2*>(&red[0][0][p]);
        float2 r01 = *reinterpret_cast<const float2*>(&red[1][0][p]);
        float2 r02 = *reinterpret_cast<const float2*>(&red[2][0][p]);
        float2 r10 = *reinterpret_cast<const float2*>(&red[0][1][p]);
        float2 r11 = *reinterpret_cast<const float2*>(&red[1][1][p]);
        float2 r12 = *reinterpret_cast<const float2*>(&red[2][1][p]);
        float2 r20 = *reinterpret_cast<const float2*>(&red[0][2][p]);
        float2 r21 = *reinterpret_cast<const float2*>(&red[1][2][p]);
        float2 r22 = *reinterpret_cast<const float2*>(&red[2][2][p]);
        *reinterpret_cast<float2*>(&ob[0]) =
            make_float2(acc0a + r00.x + r01.x + r02.x,
                        acc0b + r00.y + r01.y + r02.y);
        *reinterpret_cast<float2*>(&ob[P]) =
            make_float2(acc1a + r10.x + r11.x + r12.x,
                        acc1b + r10.y + r11.y + r12.y);
        *reinterpret_cast<float2*>(&ob[2 * P]) =
            make_float2(acc2a + r20.x + r21.x + r22.x,
                        acc2b + r20.y + r21.y + r22.y);
    }
}

extern "C" void kernel_launch(void* const* d_in, const int* in_sizes, int n_in,
                              void* d_out, int out_size, void* d_ws, size_t ws_size,
                              hipStream_t stream) {
    const float* inp  = (const float*)d_in[0];
    const float* vert = (const float*)d_in[1];
    const float* horz = (const float*)d_in[2];
    const float* offX = (const float*)d_in[3];
    const float* offY = (const float*)d_in[4];
    const float* mask = (const float*)d_in[5];
    float* out = (float*)d_out;

    // grid: B * (HO/2) * (WO/64) = 4 * 128 * 4 = 2048 blocks, 256 thr each
    dim3 block(256);
    dim3 grid(B * (HO / 2) * (WO / 64));
    dsepconv_kernel<<<grid, block, 0, stream>>>(inp, vert, horz, offX, offY, mask, out);
}

// Round 21
// 24.673 us; speedup vs baseline: 1.0630x; 1.0630x over previous
//
#include <hip/hip_runtime.h>
#include <hip/hip_fp16.h>

// Problem constants (match reference)
constexpr int B  = 4;
constexpr int C  = 3;
constexpr int F  = 5;
constexpr int HO = 256;
constexpr int WO = 256;
constexpr int HI = HO + F - 1; // 260
constexpr int WI = WO + F - 1; // 260
constexpr int P  = HO * WO;    // 65536 pixels per (b, map)
constexpr int FF = F * F;      // 25
constexpr int PI = HI * WI;    // 67600 input pixels per (b, c)

// R21 = R18 (23.49us) + ping-pong 2-deep stream prefetch with ZERO copies:
// tap loop manually unrolled x2; buffers A/B alternate at compile time
// (tap(A,k); reload A<-k+2; tap(B,k+1); reload B<-k+3). Each buffer's loads
// get ~2 tap bodies (~900cy) before use -> exposed stream latency ~0.
// (R17's rotating version regressed from 20 v_movs/tap; R18's 1-deep rotate
// forced vmcnt(0) every iteration = only 1 body of overlap.)
// Block = 256 threads = 4 waves: wave = (row in {0,1}) x (tap-half in {0,1}).
// Patch = 128 px wide x 2 rows; thread handles (x, x+1); streams are float2.
// Staging unroll 4 (R18 win). Margin 5 (R17-validated). TSTRIDE mod 16 = 5
// (R15 bank-decollision). Tap-loop persistent state ~60 VGPR at 256-thr
// blocks (128-VGPR cap) — the validated no-spill regime.
constexpr int TROWS = 17;
constexpr int TCOLS = 143;
constexpr int TSTRIDE = 149;           // 8B units
constexpr int TN = TROWS * TCOLS;      // 2431 entries to stage
constexpr int AMAX = (TROWS - 2) * TSTRIDE + (TCOLS - 2); // 2376

__device__ __forceinline__ float2 ld2(const float* p) {
    return *reinterpret_cast<const float2*>(p);
}

__device__ __forceinline__ uint2 pack3(float a, float b, float c) {
    __half2 ab = __floats2half2_rn(a, b);
    __half2 cz = __floats2half2_rn(c, 0.0f);
    uint2 r;
    r.x = *reinterpret_cast<const unsigned int*>(&ab);
    r.y = *reinterpret_cast<const unsigned int*>(&cz);
    return r;
}

__device__ __forceinline__ void fmacc(uint2 v, float w,
                                      float& a0, float& a1, float& a2) {
    __half2 ab = *reinterpret_cast<const __half2*>(&v.x);
    __half2 cz = *reinterpret_cast<const __half2*>(&v.y);
    // (float)half * f32 + f32 acc -> v_fma_mix_f32
    a0 += __half2float(__low2half(ab))  * w;
    a1 += __half2float(__high2half(ab)) * w;
    a2 += __half2float(__low2half(cz))  * w;
}

__global__ __launch_bounds__(256, 4) void dsepconv_kernel(
    const float* __restrict__ inp,   // (B, C, HI, WI)
    const float* __restrict__ vert,  // (B, F, HO, WO)
    const float* __restrict__ horz,  // (B, F, HO, WO)
    const float* __restrict__ offX,  // -> py (vertical), per reference
    const float* __restrict__ offY,  // -> px (horizontal), per reference
    const float* __restrict__ mask,  // (B, F*F, HO, WO)
    float* __restrict__ out)         // (B, C, HO, WO)
{
    __shared__ uint2 tileq[TROWS * TSTRIDE];  // 20,264 B
    __shared__ float red[2][3][128];          // 3,072 B

    const int tid  = threadIdx.x;
    const int lane = tid & 63;
    const int wave = tid >> 6;                 // 0..3
    const int wrow = wave >> 1;                // 0..1: y-row in patch
    const int half = wave & 1;                 // 0..1: tap half

    // Grid: bx = b*256 + yblk*2 + xblk ; patch origin (y0, x0)
    const int bx   = blockIdx.x;
    const int x0   = (bx & 1) * 128;
    const int y0   = ((bx >> 1) & 127) * 2;
    const int b    = bx >> 8;

    const float* in0 = inp + (size_t)b * C * PI;
    const float* in1 = in0 + PI;
    const float* in2 = in1 + PI;

    const int x   = x0 + 2 * lane;             // even; this thread: x, x+1
    const int y   = y0 + wrow;
    const int pix = y * WO + x;

    const float* offXb = offX + (size_t)b * FF * P + pix;
    const float* offYb = offY + (size_t)b * FF * P + pix;
    const float* maskb = mask + (size_t)b * FF * P + pix;
    const float* vb    = vert + (size_t)b * F * P + pix;
    const float* hb    = horz + (size_t)b * F * P + pix;

    const int k0    = half ? 12 : 0;
    const int k1    = half ? 25 : 12;
    const int klast = k1 - 1;

    // ---- Ping-pong stream buffers (named scalars -> registers) ----
    float2 oyA, oxA, mA, hA, vA;
    float2 oyB, oxB, mB, hB, vB;

    auto loadA = [&](int k) {
        const int i = k / F, j = k - (k / F) * F;
        oyA = ld2(offYb + (size_t)k * P);
        oxA = ld2(offXb + (size_t)k * P);
        mA  = ld2(maskb + (size_t)k * P);
        hA  = ld2(hb + (size_t)j * P);
        vA  = ld2(vb + (size_t)i * P);
    };
    auto loadB = [&](int k) {
        const int i = k / F, j = k - (k / F) * F;
        oyB = ld2(offYb + (size_t)k * P);
        oxB = ld2(offXb + (size_t)k * P);
        mB  = ld2(maskb + (size_t)k * P);
        hB  = ld2(hb + (size_t)j * P);
        vB  = ld2(vb + (size_t)i * P);
    };

    // 2-deep prologue: both buffers in flight before staging; the staging
    // barrier's vmcnt(0) drain completes them for free.
    loadA(k0);
    loadB(min(k0 + 1, klast));

    // ---- Stage tile: rows [y0-6, y0+10], cols [x0-6, x0+136] ----
    // Unroll 4: independent + transient -> loads pipeline, no VGPR growth.
    const int ry0 = y0 - 6;
    const int cx0 = x0 - 6;
#pragma unroll 4
    for (int e = tid; e < TN; e += 256) {
        int trow = e / TCOLS;
        int tcol = e - trow * TCOLS;
        int gy = min(max(ry0 + trow, 0), HI - 1);
        int gx = min(max(cx0 + tcol, 0), WI - 1);
        int g = gy * WI + gx;
        tileq[trow * TSTRIDE + tcol] = pack3(in0[g], in1[g], in2[g]);
    }
    __syncthreads();

    float acc0a = 0.f, acc1a = 0.f, acc2a = 0.f;
    float acc0b = 0.f, acc1b = 0.f, acc2b = 0.f;

    // ---- one tap, streams passed by value (registers) ----
    auto tap = [&](int k, float2 oy, float2 ox, float2 m, float2 h, float2 v) {
        const int i = k / F;
        const int j = k - i * F;

        // px = clip(offY + x + j - half + 1, 0, WI-1); half = 2
        float pya = fminf(fmaxf(ox.x + (float)(y + i - 1), 0.0f), (float)(HI - 1));
        float pyb = fminf(fmaxf(ox.y + (float)(y + i - 1), 0.0f), (float)(HI - 1));
        float pxa = fminf(fmaxf(oy.x + (float)(x + j - 1), 0.0f), (float)(WI - 1));
        float pxb = fminf(fmaxf(oy.y + (float)(x + j), 0.0f), (float)(WI - 1));

        float lfa = floorf(pxa), tfa = floorf(pya);
        float lfb = floorf(pxb), tfb = floorf(pyb);
        int la = (int)lfa, ta = (int)tfa;
        int lb = (int)lfb, tb = (int)tfb;
        float wxa = 1.0f - (pxa - lfa), wya = 1.0f - (pya - tfa);
        float wxb = 1.0f - (pxb - lfb), wyb = 1.0f - (pyb - tfb);

        int lta = ta - ry0, lla = la - cx0;
        int ltb = tb - ry0, llb = lb - cx0;
        bool oka = ((unsigned)lta <= TROWS - 2) & ((unsigned)lla <= TCOLS - 2);
        bool okb = ((unsigned)ltb <= TROWS - 2) & ((unsigned)llb <= TCOLS - 2);

        int aa = min(max(lta * TSTRIDE + lla, 0), AMAX);
        int ab = min(max(ltb * TSTRIDE + llb, 0), AMAX);

        // 8 gathers issue together; FMAs follow
        uint2 ga0 = tileq[aa];
        uint2 ga1 = tileq[aa + 1];
        uint2 ga2 = tileq[aa + TSTRIDE];
        uint2 ga3 = tileq[aa + TSTRIDE + 1];
        uint2 gb0 = tileq[ab];
        uint2 gb1 = tileq[ab + 1];
        uint2 gb2 = tileq[ab + TSTRIDE];
        uint2 gb3 = tileq[ab + TSTRIDE + 1];

        // rare fallback: offset beyond tile margin (~1e-6/sample)
        if (__any(!(oka & okb))) {
            if (!oka) {
                int r  = min(la + 1, WI - 1);
                int bt = min(ta + 1, HI - 1);
                int o0 = ta * WI + la, o1 = ta * WI + r;
                int o2 = bt * WI + la, o3 = bt * WI + r;
                ga0 = pack3(in0[o0], in1[o0], in2[o0]);
                ga1 = pack3(in0[o1], in1[o1], in2[o1]);
                ga2 = pack3(in0[o2], in1[o2], in2[o2]);
                ga3 = pack3(in0[o3], in1[o3], in2[o3]);
            }
            if (!okb) {
                int r  = min(lb + 1, WI - 1);
                int bt = min(tb + 1, HI - 1);
                int o0 = tb * WI + lb, o1 = tb * WI + r;
                int o2 = bt * WI + lb, o3 = bt * WI + r;
                gb0 = pack3(in0[o0], in1[o0], in2[o0]);
                gb1 = pack3(in0[o1], in1[o1], in2[o1]);
                gb2 = pack3(in0[o2], in1[o2], in2[o2]);
                gb3 = pack3(in0[o3], in1[o3], in2[o3]);
            }
        }

        // Bilinear identity: clamped edge => r/bottom weights exactly 0.
        float wA   = v.x * h.x * m.x;
        float wywA = wya * wA;
        float wbwA = wA - wywA;
        float wtlA = wxa * wywA;
        float wtrA = wywA - wtlA;
        float wblA = wxa * wbwA;
        float wbrA = wbwA - wblA;

        float wB   = v.y * h.y * m.y;
        float wywB = wyb * wB;
        float wbwB = wB - wywB;
        float wtlB = wxb * wywB;
        float wtrB = wywB - wtlB;
        float wblB = wxb * wbwB;
        float wbrB = wbwB - wblB;

        fmacc(ga0, wtlA, acc0a, acc1a, acc2a);
        fmacc(ga1, wtrA, acc0a, acc1a, acc2a);
        fmacc(ga2, wblA, acc0a, acc1a, acc2a);
        fmacc(ga3, wbrA, acc0a, acc1a, acc2a);
        fmacc(gb0, wtlB, acc0b, acc1b, acc2b);
        fmacc(gb1, wtrB, acc0b, acc1b, acc2b);
        fmacc(gb2, wblB, acc0b, acc1b, acc2b);
        fmacc(gb3, wbrB, acc0b, acc1b, acc2b);
    };

    // ---- tap loop, unrolled x2 with compile-time buffer alternation ----
    int k = k0;
#pragma unroll 1
    for (; k + 1 < k1; k += 2) {
        tap(k, oyA, oxA, mA, hA, vA);
        loadA(min(k + 2, klast));      // ~2 tap bodies before consumption
        tap(k + 1, oyB, oxB, mB, hB, vB);
        loadB(min(k + 3, klast));      // harmless duplicate near the end
    }
    if (k < k1) {                      // odd tap count (13-half) tail
        tap(k, oyA, oxA, mA, hA, vA);
    }

    // ---- Combine the two tap-halves per row (float2 traffic) ----
    if (half) {
        *reinterpret_cast<float2*>(&red[wrow][0][2 * lane]) = make_float2(acc0a, acc0b);
        *reinterpret_cast<float2*>(&red[wrow][1][2 * lane]) = make_float2(acc1a, acc1b);
        *reinterpret_cast<float2*>(&red[wrow][2][2 * lane]) = make_float2(acc2a, acc2b);
    }
    __syncthreads();

    if (!half) {
        float* ob = out + (size_t)b * C * P + pix;
        float2 r0 = *reinterpret_cast<const float2*>(&red[wrow][0][2 * lane]);
        float2 r1 = *reinterpret_cast<const float2*>(&red[wrow][1][2 * lane]);
        float2 r2 = *reinterpret_cast<const float2*>(&red[wrow][2][2 * lane]);
        *reinterpret_cast<float2*>(&ob[0])     = make_float2(acc0a + r0.x, acc0b + r0.y);
        *reinterpret_cast<float2*>(&ob[P])     = make_float2(acc1a + r1.x, acc1b + r1.y);
        *reinterpret_cast<float2*>(&ob[2 * P]) = make_float2(acc2a + r2.x, acc2b + r2.y);
    }
}

extern "C" void kernel_launch(void* const* d_in, const int* in_sizes, int n_in,
                              void* d_out, int out_size, void* d_ws, size_t ws_size,
                              hipStream_t stream) {
    const float* inp  = (const float*)d_in[0];
    const float* vert = (const float*)d_in[1];
    const float* horz = (const float*)d_in[2];
    const float* offX = (const float*)d_in[3];
    const float* offY = (const float*)d_in[4];
    const float* mask = (const float*)d_in[5];
    float* out = (float*)d_out;

    // grid: B * (HO/2) * (WO/128) = 4 * 128 * 2 = 1024 blocks, 256 thr each
    dim3 block(256);
    dim3 grid(B * (HO / 2) * (WO / 128));
    dsepconv_kernel<<<grid, block, 0, stream>>>(inp, vert, horz, offX, offY, mask, out);
}

// Round 22
// 24.127 us; speedup vs baseline: 1.0871x; 1.0227x over previous
//
#include <hip/hip_runtime.h>
#include <hip/hip_fp16.h>

// Problem constants (match reference)
constexpr int B  = 4;
constexpr int C  = 3;
constexpr int F  = 5;
constexpr int HO = 256;
constexpr int WO = 256;
constexpr int HI = HO + F - 1; // 260
constexpr int WI = WO + F - 1; // 260
constexpr int P  = HO * WO;    // 65536 pixels per (b, map)
constexpr int FF = F * F;      // 25
constexpr int PI = HI * WI;    // 67600 input pixels per (b, c)

// R22 = R18 (23.49us best) + instruction-count cuts, no structural change:
//  (1) in-loop __any+branch fallback (6 instr/tap, never taken) -> 1-instr
//      `bad |=` flag; post-loop rare exec-masked full recompute (exact).
//  (2) v/h dropped from the 1-deep prefetch rotate (L1-hot, load at use):
//      rotate 10 -> 6 v_movs/tap, 2 fewer loads on the critical vmcnt.
// Block = 256 threads = 4 waves: wave = (row in {0,1}) x (tap-half in {0,1}).
// Patch = 128 px wide x 2 rows; thread handles (x, x+1); cold streams
// (offY/offX/mask) float2, 1-deep prefetch (2-deep regressed: R17, R21).
// Staging unroll 4 (R18). Margin 5 (R17-validated). TSTRIDE mod 16 = 5 (R15).
constexpr int TROWS = 17;
constexpr int TCOLS = 143;
constexpr int TSTRIDE = 149;           // 8B units
constexpr int TN = TROWS * TCOLS;      // 2431 entries to stage
constexpr int AMAX = (TROWS - 2) * TSTRIDE + (TCOLS - 2); // 2376

__device__ __forceinline__ float2 ld2(const float* p) {
    return *reinterpret_cast<const float2*>(p);
}

__device__ __forceinline__ uint2 pack3(float a, float b, float c) {
    __half2 ab = __floats2half2_rn(a, b);
    __half2 cz = __floats2half2_rn(c, 0.0f);
    uint2 r;
    r.x = *reinterpret_cast<const unsigned int*>(&ab);
    r.y = *reinterpret_cast<const unsigned int*>(&cz);
    return r;
}

__device__ __forceinline__ void fmacc(uint2 v, float w,
                                      float& a0, float& a1, float& a2) {
    __half2 ab = *reinterpret_cast<const __half2*>(&v.x);
    __half2 cz = *reinterpret_cast<const __half2*>(&v.y);
    // (float)half * f32 + f32 acc -> v_fma_mix_f32
    a0 += __half2float(__low2half(ab))  * w;
    a1 += __half2float(__high2half(ab)) * w;
    a2 += __half2float(__low2half(cz))  * w;
}

__global__ __launch_bounds__(256, 4) void dsepconv_kernel(
    const float* __restrict__ inp,   // (B, C, HI, WI)
    const float* __restrict__ vert,  // (B, F, HO, WO)
    const float* __restrict__ horz,  // (B, F, HO, WO)
    const float* __restrict__ offX,  // -> py (vertical), per reference
    const float* __restrict__ offY,  // -> px (horizontal), per reference
    const float* __restrict__ mask,  // (B, F*F, HO, WO)
    float* __restrict__ out)         // (B, C, HO, WO)
{
    __shared__ uint2 tileq[TROWS * TSTRIDE];  // 20,264 B
    __shared__ float red[2][3][128];          // 3,072 B

    const int tid  = threadIdx.x;
    const int lane = tid & 63;
    const int wave = tid >> 6;                 // 0..3
    const int wrow = wave >> 1;                // 0..1: y-row in patch
    const int half = wave & 1;                 // 0..1: tap half

    // Grid: bx = b*256 + yblk*2 + xblk ; patch origin (y0, x0)
    const int bx   = blockIdx.x;
    const int x0   = (bx & 1) * 128;
    const int y0   = ((bx >> 1) & 127) * 2;
    const int b    = bx >> 8;

    const float* in0 = inp + (size_t)b * C * PI;
    const float* in1 = in0 + PI;
    const float* in2 = in1 + PI;

    const int x   = x0 + 2 * lane;             // even; this thread: x, x+1
    const int y   = y0 + wrow;
    const int pix = y * WO + x;

    const float* offXb = offX + (size_t)b * FF * P + pix;
    const float* offYb = offY + (size_t)b * FF * P + pix;
    const float* maskb = mask + (size_t)b * FF * P + pix;
    const float* vb    = vert + (size_t)b * F * P + pix;
    const float* hb    = horz + (size_t)b * F * P + pix;

    const int k0 = half ? 12 : 0;
    const int k1 = half ? 25 : 12;

    // ---- Prefetch first tap's COLD streams (drained by staging barrier) ----
    float2 oy, ox, m;
    oy = ld2(offYb + (size_t)k0 * P);
    ox = ld2(offXb + (size_t)k0 * P);
    m  = ld2(maskb + (size_t)k0 * P);

    // ---- Stage tile: rows [y0-6, y0+10], cols [x0-6, x0+136] ----
    const int ry0 = y0 - 6;
    const int cx0 = x0 - 6;
#pragma unroll 4
    for (int e = tid; e < TN; e += 256) {
        int trow = e / TCOLS;
        int tcol = e - trow * TCOLS;
        int gy = min(max(ry0 + trow, 0), HI - 1);
        int gx = min(max(cx0 + tcol, 0), WI - 1);
        int g = gy * WI + gx;
        tileq[trow * TSTRIDE + tcol] = pack3(in0[g], in1[g], in2[g]);
    }
    __syncthreads();   // vmcnt(0) drain also completes the stream prefetch

    float acc0a = 0.f, acc1a = 0.f, acc2a = 0.f;
    float acc0b = 0.f, acc1b = 0.f, acc2b = 0.f;
    bool bad = false;

#pragma unroll 1
    for (int k = k0; k < k1; ++k) {
        const int i = k / F;
        const int j = k - i * F;

        // ---- issue NEXT tap's cold streams (overlap with this compute) ----
        const int kn = (k + 1 < k1) ? k + 1 : k;
        float2 oy_n = ld2(offYb + (size_t)kn * P);
        float2 ox_n = ld2(offXb + (size_t)kn * P);
        float2 m_n  = ld2(maskb + (size_t)kn * P);

        // v/h: L1-hot (<=8 distinct lines per wave), load at use
        float2 h = ld2(hb + (size_t)j * P);
        float2 v = ld2(vb + (size_t)i * P);

        // ---- coords, pixel A (x) and B (x+1) ----
        // px = clip(offY + x + j - half + 1, 0, WI-1); half = 2
        float pya = fminf(fmaxf(ox.x + (float)(y + i - 1), 0.0f), (float)(HI - 1));
        float pyb = fminf(fmaxf(ox.y + (float)(y + i - 1), 0.0f), (float)(HI - 1));
        float pxa = fminf(fmaxf(oy.x + (float)(x + j - 1), 0.0f), (float)(WI - 1));
        float pxb = fminf(fmaxf(oy.y + (float)(x + j), 0.0f), (float)(WI - 1));

        float lfa = floorf(pxa), tfa = floorf(pya);
        float lfb = floorf(pxb), tfb = floorf(pyb);
        int la = (int)lfa, ta = (int)tfa;
        int lb = (int)lfb, tb = (int)tfb;
        float wxa = 1.0f - (pxa - lfa), wya = 1.0f - (pya - tfa);
        float wxb = 1.0f - (pxb - lfb), wyb = 1.0f - (pyb - tfb);

        int lta = ta - ry0, lla = la - cx0;
        int ltb = tb - ry0, llb = lb - cx0;
        // cheap guard: flag only; rare recompute post-loop
        bad |= !(((unsigned)lta <= TROWS - 2) & ((unsigned)lla <= TCOLS - 2) &
                 ((unsigned)ltb <= TROWS - 2) & ((unsigned)llb <= TCOLS - 2));

        int aa = min(max(lta * TSTRIDE + lla, 0), AMAX);
        int ab = min(max(ltb * TSTRIDE + llb, 0), AMAX);

        // ---- 8 gathers issue together; FMAs follow ----
        uint2 ga0 = tileq[aa];
        uint2 ga1 = tileq[aa + 1];
        uint2 ga2 = tileq[aa + TSTRIDE];
        uint2 ga3 = tileq[aa + TSTRIDE + 1];
        uint2 gb0 = tileq[ab];
        uint2 gb1 = tileq[ab + 1];
        uint2 gb2 = tileq[ab + TSTRIDE];
        uint2 gb3 = tileq[ab + TSTRIDE + 1];

        // Bilinear identity: clamped edge => r/bottom weights exactly 0.
        float wA   = v.x * h.x * m.x;
        float wywA = wya * wA;
        float wbwA = wA - wywA;
        float wtlA = wxa * wywA;
        float wtrA = wywA - wtlA;
        float wblA = wxa * wbwA;
        float wbrA = wbwA - wblA;

        float wB   = v.y * h.y * m.y;
        float wywB = wyb * wB;
        float wbwB = wB - wywB;
        float wtlB = wxb * wywB;
        float wtrB = wywB - wtlB;
        float wblB = wxb * wbwB;
        float wbrB = wbwB - wblB;

        fmacc(ga0, wtlA, acc0a, acc1a, acc2a);
        fmacc(ga1, wtrA, acc0a, acc1a, acc2a);
        fmacc(ga2, wblA, acc0a, acc1a, acc2a);
        fmacc(ga3, wbrA, acc0a, acc1a, acc2a);
        fmacc(gb0, wtlB, acc0b, acc1b, acc2b);
        fmacc(gb1, wtrB, acc0b, acc1b, acc2b);
        fmacc(gb2, wblB, acc0b, acc1b, acc2b);
        fmacc(gb3, wbrB, acc0b, acc1b, acc2b);

        // ---- rotate cold-stream pipeline (6 movs) ----
        oy = oy_n; ox = ox_n; m = m_n;
    }

    // ---- rare path: some tap sampled beyond the tile margin (~1e-6) ----
    // Recompute this lane's ENTIRE output from global memory (exact; the
    // polluted LDS-path accumulators are discarded). Exec-masked per lane.
    if (__any(bad)) {
        if (bad) {
            acc0a = acc1a = acc2a = 0.f;
            acc0b = acc1b = acc2b = 0.f;
#pragma unroll 1
            for (int k = k0; k < k1; ++k) {
                const int i = k / F;
                const int j = k - i * F;
                float2 oyr = ld2(offYb + (size_t)k * P);
                float2 oxr = ld2(offXb + (size_t)k * P);
                float2 mr  = ld2(maskb + (size_t)k * P);
                float2 hr  = ld2(hb + (size_t)j * P);
                float2 vr  = ld2(vb + (size_t)i * P);
#pragma unroll
                for (int s = 0; s < 2; ++s) {
                    float oys = s ? oyr.y : oyr.x;
                    float oxs = s ? oxr.y : oxr.x;
                    float ws  = (s ? vr.y * hr.y * mr.y : vr.x * hr.x * mr.x);
                    float px = fminf(fmaxf(oys + (float)(x + s + j - 1), 0.0f), (float)(WI - 1));
                    float py = fminf(fmaxf(oxs + (float)(y + i - 1), 0.0f), (float)(HI - 1));
                    float lf = floorf(px), tf = floorf(py);
                    int l = (int)lf, t = (int)tf;
                    int r  = min(l + 1, WI - 1);
                    int bt = min(t + 1, HI - 1);
                    float wx = 1.0f - (px - lf);
                    float wy = 1.0f - (py - tf);
                    float wtl = wx * wy * ws;
                    float wtr = (1.0f - wx) * wy * ws;
                    float wbl = wx * (1.0f - wy) * ws;
                    float wbr = (1.0f - wx) * (1.0f - wy) * ws;
                    int o0 = t * WI + l,  o1 = t * WI + r;
                    int o2 = bt * WI + l, o3 = bt * WI + r;
                    float g0c0 = in0[o0], g1c0 = in0[o1], g2c0 = in0[o2], g3c0 = in0[o3];
                    float g0c1 = in1[o0], g1c1 = in1[o1], g2c1 = in1[o2], g3c1 = in1[o3];
                    float g0c2 = in2[o0], g1c2 = in2[o1], g2c2 = in2[o2], g3c2 = in2[o3];
                    float s0 = g0c0 * wtl + g1c0 * wtr + g2c0 * wbl + g3c0 * wbr;
                    float s1 = g0c1 * wtl + g1c1 * wtr + g2c1 * wbl + g3c1 * wbr;
                    float s2 = g0c2 * wtl + g1c2 * wtr + g2c2 * wbl + g3c2 * wbr;
                    if (s) { acc0b += s0; acc1b += s1; acc2b += s2; }
                    else   { acc0a += s0; acc1a += s1; acc2a += s2; }
                }
            }
        }
    }

    // ---- Combine the two tap-halves per row (float2 traffic) ----
    if (half) {
        *reinterpret_cast<float2*>(&red[wrow][0][2 * lane]) = make_float2(acc0a, acc0b);
        *reinterpret_cast<float2*>(&red[wrow][1][2 * lane]) = make_float2(acc1a, acc1b);
        *reinterpret_cast<float2*>(&red[wrow][2][2 * lane]) = make_float2(acc2a, acc2b);
    }
    __syncthreads();

    if (!half) {
        float* ob = out + (size_t)b * C * P + pix;
        float2 r0 = *reinterpret_cast<const float2*>(&red[wrow][0][2 * lane]);
        float2 r1 = *reinterpret_cast<const float2*>(&red[wrow][1][2 * lane]);
        float2 r2 = *reinterpret_cast<const float2*>(&red[wrow][2][2 * lane]);
        *reinterpret_cast<float2*>(&ob[0])     = make_float2(acc0a + r0.x, acc0b + r0.y);
        *reinterpret_cast<float2*>(&ob[P])     = make_float2(acc1a + r1.x, acc1b + r1.y);
        *reinterpret_cast<float2*>(&ob[2 * P]) = make_float2(acc2a + r2.x, acc2b + r2.y);
    }
}

extern "C" void kernel_launch(void* const* d_in, const int* in_sizes, int n_in,
                              void* d_out, int out_size, void* d_ws, size_t ws_size,
                              hipStream_t stream) {
    const float* inp  = (const float*)d_in[0];
    const float* vert = (const float*)d_in[1];
    const float* horz = (const float*)d_in[2];
    const float* offX = (const float*)d_in[3];
    const float* offY = (const float*)d_in[4];
    const float* mask = (const float*)d_in[5];
    float* out = (float*)d_out;

    // grid: B * (HO/2) * (WO/128) = 4 * 128 * 2 = 1024 blocks, 256 thr each
    dim3 block(256);
    dim3 grid(B * (HO / 2) * (WO / 128));
    dsepconv_kernel<<<grid, block, 0, stream>>>(inp, vert, horz, offX, offY, mask, out);
}